// Round 9
// baseline (423.294 us; speedup 1.0000x reference)
//
#include <hip/hip_runtime.h>
#include <stdint.h>

// out = (adj @ (X@W + b)) / rowsum(adj)
// B=8, N=4096, C_IN=C_OUT=512, all fp32 in/out. bf16 MFMA internally.
// ws: hT bf16 [8][512][4096] (32 MiB), Wt bf16 [512][512] after.

typedef __attribute__((ext_vector_type(4))) float  f32x4;
typedef __attribute__((ext_vector_type(8))) __bf16 bf16x8;
typedef __attribute__((ext_vector_type(4))) __bf16 bf16x4;

#define GLOAD_LDS16(gsrc, ldst)                                                           \
  __builtin_amdgcn_global_load_lds((const __attribute__((address_space(1))) void*)(gsrc), \
                                   (__attribute__((address_space(3))) void*)(ldst), 16, 0, 0)

#define BARRIER                                  \
  do {                                           \
    asm volatile("" ::: "memory");               \
    __builtin_amdgcn_s_barrier();                \
    asm volatile("" ::: "memory");               \
  } while (0)

// ---------------- K0: Wt[n][k] = bf16(W[k][n]), 512x512 ----------------
__global__ void __launch_bounds__(256) k_wt(const float* __restrict__ W,
                                            __bf16* __restrict__ Wt) {
  __shared__ __bf16 t[64][65];
  const int k0 = blockIdx.x * 64, n0 = blockIdx.y * 64;
  const int tid = threadIdx.x;
  const int r = tid >> 2, c4 = (tid & 3) * 16;
#pragma unroll
  for (int j = 0; j < 4; ++j) {
    f32x4 v = *reinterpret_cast<const f32x4*>(W + (size_t)(k0 + r) * 512 + n0 + c4 + j * 4);
#pragma unroll
    for (int q = 0; q < 4; ++q) t[c4 + j * 4 + q][r] = (__bf16)v[q];
  }
  __syncthreads();
#pragma unroll
  for (int j = 0; j < 4; ++j) {
    bf16x4 o;
#pragma unroll
    for (int q = 0; q < 4; ++q) o[q] = t[r][c4 + j * 4 + q];
    *reinterpret_cast<bf16x4*>(Wt + (size_t)(n0 + r) * 512 + k0 + c4 + j * 4) = o;
  }
}

// ---------------- K1: proj  h = X@W + b, stored transposed as hT[b][o][m] bf16 -----
__global__ void __launch_bounds__(256) k_proj(const float* __restrict__ X,
                                              const __bf16* __restrict__ Wt,
                                              const float* __restrict__ bias,
                                              __bf16* __restrict__ hT) {
  __shared__ __attribute__((aligned(16))) __bf16 Xs[128][72];
  __shared__ __attribute__((aligned(16))) __bf16 Ws[128][72];
  const int n0 = blockIdx.x * 128;
  const int m0 = blockIdx.y * 128;
  const int tid = threadIdx.x;
  const int lane = tid & 63, w = tid >> 6;
  const int wr = w >> 1, wc = w & 1;
  const int srow = tid >> 1, scb = (tid & 1) * 32;

  f32x4 acc[4][4] = {};

  for (int k0 = 0; k0 < 512; k0 += 64) {
    const float* xp = X + (size_t)(m0 + srow) * 512 + k0 + scb;
    f32x4 xv[8];
#pragma unroll
    for (int j = 0; j < 8; ++j) xv[j] = *reinterpret_cast<const f32x4*>(xp + j * 4);
#pragma unroll
    for (int q = 0; q < 4; ++q) {
      bf16x8 o;
#pragma unroll
      for (int e = 0; e < 8; ++e) { const int idx = q * 8 + e; o[e] = (__bf16)xv[idx >> 2][idx & 3]; }
      *reinterpret_cast<bf16x8*>(&Xs[srow][scb + q * 8]) = o;
    }
    const __bf16* wp = Wt + (size_t)(n0 + srow) * 512 + k0 + scb;
#pragma unroll
    for (int q = 0; q < 4; ++q)
      *reinterpret_cast<bf16x8*>(&Ws[srow][scb + q * 8]) =
          *reinterpret_cast<const bf16x8*>(wp + q * 8);
    __syncthreads();

    for (int kk = 0; kk < 64; kk += 32) {
      const int ko = kk + ((lane >> 4) << 3);
      bf16x8 a[4], bb[4];
#pragma unroll
      for (int i = 0; i < 4; ++i)
        a[i] = *reinterpret_cast<const bf16x8*>(&Xs[wr * 64 + i * 16 + (lane & 15)][ko]);
#pragma unroll
      for (int j = 0; j < 4; ++j)
        bb[j] = *reinterpret_cast<const bf16x8*>(&Ws[wc * 64 + j * 16 + (lane & 15)][ko]);
#pragma unroll
      for (int i = 0; i < 4; ++i)
#pragma unroll
        for (int j = 0; j < 4; ++j)
          acc[i][j] = __builtin_amdgcn_mfma_f32_16x16x32_bf16(a[i], bb[j], acc[i][j], 0, 0, 0);
    }
    __syncthreads();
  }

  float bj[4];
#pragma unroll
  for (int j = 0; j < 4; ++j) bj[j] = bias[n0 + wc * 64 + j * 16 + (lane & 15)];
  const int batch = m0 >> 12;
  const int mloc0 = (m0 & 4095) + wr * 64;
#pragma unroll
  for (int i = 0; i < 4; ++i) {
    const int m_in = mloc0 + i * 16 + ((lane >> 4) << 2);
#pragma unroll
    for (int j = 0; j < 4; ++j) {
      const int n = n0 + wc * 64 + j * 16 + (lane & 15);
      bf16x4 o;
#pragma unroll
      for (int r = 0; r < 4; ++r) o[r] = (__bf16)(acc[i][j][r] + bj[j]);
      *reinterpret_cast<bf16x4*>(hT + ((size_t)batch * 512 + n) * 4096 + m_in) = o;
    }
  }
}

// ---------------- K2: aggregation, decoupled-stream pipeline -----------------------
// BM=128 x BN=512 (adj read once), BK=64, 16 waves (2x8), wave tile 64x64.
// As dbuf 2x16K + Hs dbuf 2x64K = 160 KiB, 16 waves/CU.
// R8 lesson: tile-end vmcnt(0) also drained the HBM-slow adj loads (in-order
// retire) -> HBM stream and compute ALTERNATED. Now: Hs gloads issued FIRST,
// adj NT loads second, prefetched 2 tiles ahead (ping-pong avA/avB, static
// names per rule 20). Tile-end wait = vmcnt(2): Hs published, adj stays in
// flight across the barrier. write_as after compute (max lead time).
__global__ void __launch_bounds__(1024, 4) k_agg(const float* __restrict__ adj,
                                                 const __bf16* __restrict__ hT,
                                                 float* __restrict__ out) {
  __shared__ __attribute__((aligned(16))) char lds[163840];
  char* As0 = lds;
  char* As1 = lds + 16384;
  char* Hs0 = lds + 32768;
  char* Hs1 = lds + 98304;

  const int bx = ((int)blockIdx.x & 7) * 32 + ((int)blockIdx.x >> 3);  // XCD x <-> batch x
  const int batch = bx >> 5;
  const int m0 = (bx & 31) * 128;
  const int tid = threadIdx.x;
  const int lane = tid & 63, w = tid >> 6;
  const int wr = w >> 3, wc = w & 7;  // wave tile: rows wr*64, cols wc*64

  const float*  adjb = adj + (size_t)batch * 4096 * 4096;
  const __bf16* hTb  = hT + (size_t)batch * 512 * 4096;
  float* outb = out + (size_t)batch * 4096 * 512;

  // A staging: thread -> row tid>>3, 8 cols from (tid&7)*8, XOR-swizzled write
  const int arow = tid >> 3;
  const int acb  = (tid & 7) * 8;
  const int aw   = arow * 128 + (((acb * 2)) ^ ((arow & 7) << 4));
  const float* adjrow = adjb + (size_t)(m0 + arow) * 4096 + acb;

  // Hs gload source pre-swizzle (verified): lane writes 16B block (l&7) of row l>>3
  const int srcblk = (((lane & 7) ^ ((lane >> 3) & 7)) << 3);
  const int hrow_l = (lane >> 3);

  // fragment read swizzle
  const int koffbase = (lane >> 4) << 3;
  const int kswz = (lane & 7) << 4;

  f32x4 acc[4][4] = {};
  float pdeg = 0.f;
  f32x4 avA[2], avB[2];

  auto load_adj = [&](f32x4 (&v)[2], int k0) {  // NT: single-use stream
    v[0] = __builtin_nontemporal_load(reinterpret_cast<const f32x4*>(adjrow + k0));
    v[1] = __builtin_nontemporal_load(reinterpret_cast<const f32x4*>(adjrow + k0 + 4));
  };
  auto issue_hs = [&](int k0, char* Hn) {  // 4 chunks of 1 KiB per wave
#pragma unroll
    for (int q = 0; q < 4; ++q) {
      const int c = w * 4 + q;
      const __bf16* src = hTb + (size_t)(c * 8 + hrow_l) * 4096 + k0 + srcblk;
      GLOAD_LDS16(src, Hn + c * 1024);
    }
  };
  auto write_as = [&](char* An, f32x4 (&v)[2]) {  // compiler-precise vmcnt for v
    bf16x8 o0;
#pragma unroll
    for (int e = 0; e < 8; ++e) o0[e] = (__bf16)v[e >> 2][e & 3];
    float s = 0.f;
#pragma unroll
    for (int e = 0; e < 8; ++e) s += v[e >> 2][e & 3];
    pdeg += s;
    *reinterpret_cast<bf16x8*>(An + aw) = o0;
  };
  auto compute = [&](const char* Ac, const char* Hc) {
#pragma unroll
    for (int kk = 0; kk < 64; kk += 32) {
      const int ko2 = ((kk + koffbase) * 2) ^ kswz;
      bf16x8 a[4], bb[4];
#pragma unroll
      for (int i = 0; i < 4; ++i) {
        const int row = wr * 64 + i * 16 + (lane & 15);
        a[i] = *reinterpret_cast<const bf16x8*>(Ac + row * 128 + ko2);
      }
#pragma unroll
      for (int j = 0; j < 4; ++j) {
        const int orow = wc * 64 + j * 16 + (lane & 15);
        bb[j] = *reinterpret_cast<const bf16x8*>(Hc + orow * 128 + ko2);
      }
#pragma unroll
      for (int i = 0; i < 4; ++i)
#pragma unroll
        for (int j = 0; j < 4; ++j)
          acc[i][j] = __builtin_amdgcn_mfma_f32_16x16x32_bf16(a[i], bb[j], acc[i][j], 0, 0, 0);
    }
  };

  // tile body: compute tile t, stage tile t+1 (Hs first, adj(t+2) second).
  // avU holds adj(t+1) (loaded 1 tile ago); avL receives adj(t+2).
  auto tile_body = [&](int t, f32x4 (&avU)[2], f32x4 (&avL)[2], bool doLoad) {
    const int cur = t & 1;
    const char* Ac = cur ? As1 : As0;
    const char* Hc = cur ? Hs1 : Hs0;
    char* An = cur ? As0 : As1;
    char* Hn = cur ? Hs0 : Hs1;

    issue_hs((t + 1) * 64, Hn);               // 4 VMEM, L2-fast, WAR-safe post-barrier
    if (doLoad) load_adj(avL, (t + 2) * 64);  // 2 VMEM, HBM-slow, 2 tiles of slack
    compute(Ac, Hc);                          // overlaps all 6 in-flight VMEM
    write_as(An, avU);                        // precise wait: avU issued 1 tile + compute ago
    if (doLoad) { asm volatile("s_waitcnt vmcnt(2)" ::: "memory"); }  // Hs done, adj flies on
    else        { asm volatile("s_waitcnt vmcnt(0)" ::: "memory"); }
    asm volatile("s_waitcnt lgkmcnt(0)" ::: "memory");
    BARRIER;
  };

  // ---- prologue: stage tile 0 fully; leave adj(tile1) in flight ----
  issue_hs(0, Hs0);
  load_adj(avA, 0);
  write_as(As0, avA);       // waits adj(0); drains Hs(0) too (one-time)
  load_adj(avA, 64);        // adj for tile 1, stays in flight
  asm volatile("s_waitcnt vmcnt(2)" ::: "memory");
  asm volatile("s_waitcnt lgkmcnt(0)" ::: "memory");
  BARRIER;

  // ---- main loop: tiles 0..61 in ping-pong pairs, then 62 (no further adj) ----
  for (int tp = 0; tp < 31; ++tp) {
    tile_body(2 * tp,     avA, avB, true);
    tile_body(2 * tp + 1, avB, avA, true);
  }
  tile_body(62, avA, avB, false);

  // ---- last tile (t=63, buffers idx 1) ----
  compute(As1, Hs1);

  // ---- degree: 8 partials per row, shfl + reused LDS ----
  float d = pdeg;
  d += __shfl_xor(d, 1, 64);
  d += __shfl_xor(d, 2, 64);
  d += __shfl_xor(d, 4, 64);
  __syncthreads();  // all compute done; As region free for reuse
  if ((tid & 7) == 0) reinterpret_cast<float*>(lds)[arow] = d;
  __syncthreads();
  const float* degf = reinterpret_cast<const float*>(lds);

  // ---- epilogue: divide, NT store fp32 ----
#pragma unroll
  for (int i = 0; i < 4; ++i) {
    const int rbase = wr * 64 + i * 16 + ((lane >> 4) << 2);
    float rd[4];
#pragma unroll
    for (int r = 0; r < 4; ++r) rd[r] = 1.0f / degf[rbase + r];
#pragma unroll
    for (int j = 0; j < 4; ++j) {
      const int o = wc * 64 + j * 16 + (lane & 15);
#pragma unroll
      for (int r = 0; r < 4; ++r)
        __builtin_nontemporal_store(acc[i][j][r] * rd[r],
                                    &outb[(size_t)(m0 + rbase + r) * 512 + o]);
    }
  }
}

extern "C" void kernel_launch(void* const* d_in, const int* in_sizes, int n_in,
                              void* d_out, int out_size, void* d_ws, size_t ws_size,
                              hipStream_t stream) {
  (void)in_sizes; (void)n_in; (void)out_size; (void)ws_size;
  const float* X    = (const float*)d_in[0];  // [8,4096,512]
  const float* adj  = (const float*)d_in[1];  // [8,4096,4096]
  const float* W    = (const float*)d_in[2];  // [512,512]
  const float* bias = (const float*)d_in[3];  // [512]
  float* out = (float*)d_out;                 // [8,4096,512] fp32

  char* ws = (char*)d_ws;
  __bf16* hT = (__bf16*)ws;                                   // 32 MiB
  __bf16* Wt = (__bf16*)(ws + (size_t)32 * 1024 * 1024);      // 512 KiB

  k_wt<<<dim3(8, 8), 256, 0, stream>>>(W, Wt);
  k_proj<<<dim3(4, 256), 256, 0, stream>>>(X, Wt, bias, hT);
  k_agg<<<dim3(256), 1024, 0, stream>>>(adj, hT, out);
}

// Round 11
// 271.536 us; speedup vs baseline: 1.5589x; 1.5589x over previous
//
#include <hip/hip_runtime.h>
#include <stdint.h>

// out = (adj @ (X@W + b)) / rowsum(adj)
// B=8, N=4096, C_IN=C_OUT=512, all fp32 in/out. bf16 MFMA internally.
// ws: hT bf16 [8][512][4096] (32 MiB), Wt bf16 [512][512] after.

typedef __attribute__((ext_vector_type(4))) float  f32x4;
typedef __attribute__((ext_vector_type(8))) __bf16 bf16x8;
typedef __attribute__((ext_vector_type(4))) __bf16 bf16x4;

#define GLOAD_LDS16(gsrc, ldst)                                                           \
  __builtin_amdgcn_global_load_lds((const __attribute__((address_space(1))) void*)(gsrc), \
                                   (__attribute__((address_space(3))) void*)(ldst), 16, 0, 0)

#define BARRIER                                  \
  do {                                           \
    asm volatile("" ::: "memory");               \
    __builtin_amdgcn_s_barrier();                \
    asm volatile("" ::: "memory");               \
  } while (0)

// ---------------- K0: Wt[n][k] = bf16(W[k][n]), 512x512 ----------------
__global__ void __launch_bounds__(256) k_wt(const float* __restrict__ W,
                                            __bf16* __restrict__ Wt) {
  __shared__ __bf16 t[64][65];
  const int k0 = blockIdx.x * 64, n0 = blockIdx.y * 64;
  const int tid = threadIdx.x;
  const int r = tid >> 2, c4 = (tid & 3) * 16;
#pragma unroll
  for (int j = 0; j < 4; ++j) {
    f32x4 v = *reinterpret_cast<const f32x4*>(W + (size_t)(k0 + r) * 512 + n0 + c4 + j * 4);
#pragma unroll
    for (int q = 0; q < 4; ++q) t[c4 + j * 4 + q][r] = (__bf16)v[q];
  }
  __syncthreads();
#pragma unroll
  for (int j = 0; j < 4; ++j) {
    bf16x4 o;
#pragma unroll
    for (int q = 0; q < 4; ++q) o[q] = t[r][c4 + j * 4 + q];
    *reinterpret_cast<bf16x4*>(Wt + (size_t)(n0 + r) * 512 + k0 + c4 + j * 4) = o;
  }
}

// ---------------- K1: proj  h = X@W + b, stored transposed as hT[b][o][m] bf16 -----
__global__ void __launch_bounds__(256) k_proj(const float* __restrict__ X,
                                              const __bf16* __restrict__ Wt,
                                              const float* __restrict__ bias,
                                              __bf16* __restrict__ hT) {
  __shared__ __attribute__((aligned(16))) __bf16 Xs[128][72];
  __shared__ __attribute__((aligned(16))) __bf16 Ws[128][72];
  const int n0 = blockIdx.x * 128;
  const int m0 = blockIdx.y * 128;
  const int tid = threadIdx.x;
  const int lane = tid & 63, w = tid >> 6;
  const int wr = w >> 1, wc = w & 1;
  const int srow = tid >> 1, scb = (tid & 1) * 32;

  f32x4 acc[4][4] = {};

  for (int k0 = 0; k0 < 512; k0 += 64) {
    const float* xp = X + (size_t)(m0 + srow) * 512 + k0 + scb;
    f32x4 xv[8];
#pragma unroll
    for (int j = 0; j < 8; ++j) xv[j] = *reinterpret_cast<const f32x4*>(xp + j * 4);
#pragma unroll
    for (int q = 0; q < 4; ++q) {
      bf16x8 o;
#pragma unroll
      for (int e = 0; e < 8; ++e) { const int idx = q * 8 + e; o[e] = (__bf16)xv[idx >> 2][idx & 3]; }
      *reinterpret_cast<bf16x8*>(&Xs[srow][scb + q * 8]) = o;
    }
    const __bf16* wp = Wt + (size_t)(n0 + srow) * 512 + k0 + scb;
#pragma unroll
    for (int q = 0; q < 4; ++q)
      *reinterpret_cast<bf16x8*>(&Ws[srow][scb + q * 8]) =
          *reinterpret_cast<const bf16x8*>(wp + q * 8);
    __syncthreads();

    for (int kk = 0; kk < 64; kk += 32) {
      const int ko = kk + ((lane >> 4) << 3);
      bf16x8 a[4], bb[4];
#pragma unroll
      for (int i = 0; i < 4; ++i)
        a[i] = *reinterpret_cast<const bf16x8*>(&Xs[wr * 64 + i * 16 + (lane & 15)][ko]);
#pragma unroll
      for (int j = 0; j < 4; ++j)
        bb[j] = *reinterpret_cast<const bf16x8*>(&Ws[wc * 64 + j * 16 + (lane & 15)][ko]);
#pragma unroll
      for (int i = 0; i < 4; ++i)
#pragma unroll
        for (int j = 0; j < 4; ++j)
          acc[i][j] = __builtin_amdgcn_mfma_f32_16x16x32_bf16(a[i], bb[j], acc[i][j], 0, 0, 0);
    }
    __syncthreads();
  }

  float bj[4];
#pragma unroll
  for (int j = 0; j < 4; ++j) bj[j] = bias[n0 + wc * 64 + j * 16 + (lane & 15)];
  const int batch = m0 >> 12;
  const int mloc0 = (m0 & 4095) + wr * 64;
#pragma unroll
  for (int i = 0; i < 4; ++i) {
    const int m_in = mloc0 + i * 16 + ((lane >> 4) << 2);
#pragma unroll
    for (int j = 0; j < 4; ++j) {
      const int n = n0 + wc * 64 + j * 16 + (lane & 15);
      bf16x4 o;
#pragma unroll
      for (int r = 0; r < 4; ++r) o[r] = (__bf16)(acc[i][j][r] + bj[j]);
      *reinterpret_cast<bf16x4*>(hT + ((size_t)batch * 512 + n) * 4096 + m_in) = o;
    }
  }
}

// ---------------- K2: aggregation, decoupled streams w/ PINNED issue order ---------
// BM=128 x BN=512 (adj read once), BK=64, 16 waves (2x8), wave tile 64x64.
// As dbuf 2x16K + Hs dbuf 2x64K = 160 KiB, 16 waves/CU.
// R10 lesson: counted vmcnt is order-dependent; the compiler reordered the adj
// loads before the Hs gloads (different addr spaces, no alias) so vmcnt(2)
// stranded 2 Hs gloads in flight across the barrier -> race. Fix:
//  (1) sched_barrier(0) between issue_hs and adj loads pins the queue order
//      to [.., Hs x4, adj x2]; vmcnt(2) then provably drains exactly Hs.
//  (2) manual 2-unroll with static ping-pong regs avA/avB (no reg copy, which
//      forced a hidden vmcnt(0); no lambda-by-ref, R9 lesson).
// Per tile: issue Hs(t+1) | pin | issue adj(t+2) | compute | write As(t+1)
// [precise vmcnt(6) for adj(t+1)] | vmcnt(2) lgkm(0) barrier. adj stream
// never drains at a barrier.
__global__ void __launch_bounds__(1024, 4) k_agg(const float* __restrict__ adj,
                                                 const __bf16* __restrict__ hT,
                                                 float* __restrict__ out) {
  __shared__ __attribute__((aligned(16))) char lds[163840];
  char* As0 = lds;
  char* As1 = lds + 16384;
  char* Hs0 = lds + 32768;
  char* Hs1 = lds + 98304;

  const int bx = ((int)blockIdx.x & 7) * 32 + ((int)blockIdx.x >> 3);  // XCD x <-> batch x
  const int batch = bx >> 5;
  const int m0 = (bx & 31) * 128;
  const int tid = threadIdx.x;
  const int lane = tid & 63, w = tid >> 6;
  const int wr = w >> 3, wc = w & 7;  // wave tile: rows wr*64, cols wc*64

  const float*  adjb = adj + (size_t)batch * 4096 * 4096;
  const __bf16* hTb  = hT + (size_t)batch * 512 * 4096;
  float* outb = out + (size_t)batch * 4096 * 512;

  // A staging: thread -> row tid>>3, 8 cols from (tid&7)*8, XOR-swizzled write
  const int arow = tid >> 3;
  const int acb  = (tid & 7) * 8;
  const int aw   = arow * 128 + (((acb * 2)) ^ ((arow & 7) << 4));
  const float* adjrow = adjb + (size_t)(m0 + arow) * 4096 + acb;

  // Hs gload source pre-swizzle (verified): lane writes 16B block (l&7) of row l>>3
  const int srcblk = (((lane & 7) ^ ((lane >> 3) & 7)) << 3);
  const int hrow_l = (lane >> 3);

  // fragment read swizzle
  const int koffbase = (lane >> 4) << 3;
  const int kswz = (lane & 7) << 4;

  f32x4 acc[4][4] = {};
  float pdeg = 0.f;
  f32x4 avA0, avA1, avB0, avB1;  // static ping-pong names, no arrays, no copies

  auto issue_hs = [&](int k0, char* Hn) {  // 4 chunks of 1 KiB per wave
#pragma unroll
    for (int q = 0; q < 4; ++q) {
      const int c = w * 4 + q;
      const __bf16* src = hTb + (size_t)(c * 8 + hrow_l) * 4096 + k0 + srcblk;
      GLOAD_LDS16(src, Hn + c * 1024);
    }
  };
  auto compute = [&](const char* Ac, const char* Hc) {
#pragma unroll
    for (int kk = 0; kk < 64; kk += 32) {
      const int ko2 = ((kk + koffbase) * 2) ^ kswz;
      bf16x8 a[4], bb[4];
#pragma unroll
      for (int i = 0; i < 4; ++i) {
        const int row = wr * 64 + i * 16 + (lane & 15);
        a[i] = *reinterpret_cast<const bf16x8*>(Ac + row * 128 + ko2);
      }
#pragma unroll
      for (int j = 0; j < 4; ++j) {
        const int orow = wc * 64 + j * 16 + (lane & 15);
        bb[j] = *reinterpret_cast<const bf16x8*>(Hc + orow * 128 + ko2);
      }
#pragma unroll
      for (int i = 0; i < 4; ++i)
#pragma unroll
        for (int j = 0; j < 4; ++j)
          acc[i][j] = __builtin_amdgcn_mfma_f32_16x16x32_bf16(a[i], bb[j], acc[i][j], 0, 0, 0);
    }
  };

// tile body: compute tile T, stage Hs(T+1)+As(T+1), prefetch adj(T+2) into AVL.
// AVU holds adj(T+1). DOLOAD is a compile-time constant per expansion.
#define TILE_BODY(T, AVU0, AVU1, AVL0, AVL1, DOLOAD)                                      \
  do {                                                                                    \
    const int cur_ = (T) & 1;                                                             \
    const char* Ac_ = cur_ ? As1 : As0;                                                   \
    const char* Hc_ = cur_ ? Hs1 : Hs0;                                                   \
    char* An_ = cur_ ? As0 : As1;                                                         \
    char* Hn_ = cur_ ? Hs0 : Hs1;                                                         \
    issue_hs(((T) + 1) * 64, Hn_);                                                        \
    __builtin_amdgcn_sched_barrier(0); /* pin queue: Hs x4 BEFORE adj x2 */               \
    if (DOLOAD) {                                                                         \
      AVL0 = __builtin_nontemporal_load(                                                  \
          reinterpret_cast<const f32x4*>(adjrow + ((T) + 2) * 64));                       \
      AVL1 = __builtin_nontemporal_load(                                                  \
          reinterpret_cast<const f32x4*>(adjrow + ((T) + 2) * 64 + 4));                   \
    }                                                                                     \
    compute(Ac_, Hc_);                                                                    \
    {                                                                                     \
      bf16x8 o0_;                                                                         \
      _Pragma("unroll") for (int e = 0; e < 4; ++e) o0_[e] = (__bf16)AVU0[e];             \
      _Pragma("unroll") for (int e = 0; e < 4; ++e) o0_[4 + e] = (__bf16)AVU1[e];         \
      pdeg += AVU0[0] + AVU0[1] + AVU0[2] + AVU0[3] +                                     \
              AVU1[0] + AVU1[1] + AVU1[2] + AVU1[3];                                      \
      *reinterpret_cast<bf16x8*>(An_ + aw) = o0_;                                         \
    }                                                                                     \
    if (DOLOAD) { asm volatile("s_waitcnt vmcnt(2)" ::: "memory"); }                      \
    else        { asm volatile("s_waitcnt vmcnt(0)" ::: "memory"); }                      \
    asm volatile("s_waitcnt lgkmcnt(0)" ::: "memory");                                    \
    BARRIER;                                                                              \
  } while (0)

  // ---- prologue: stage tile 0; leave adj(1) in flight ----
  issue_hs(0, Hs0);
  __builtin_amdgcn_sched_barrier(0);
  avA0 = __builtin_nontemporal_load(reinterpret_cast<const f32x4*>(adjrow));
  avA1 = __builtin_nontemporal_load(reinterpret_cast<const f32x4*>(adjrow + 4));
  {  // write As(0): backend waits precisely for adj(0) (drains Hs(0) too; one-time)
    bf16x8 o0;
#pragma unroll
    for (int e = 0; e < 4; ++e) o0[e] = (__bf16)avA0[e];
#pragma unroll
    for (int e = 0; e < 4; ++e) o0[4 + e] = (__bf16)avA1[e];
    pdeg += avA0[0] + avA0[1] + avA0[2] + avA0[3] +
            avA1[0] + avA1[1] + avA1[2] + avA1[3];
    *reinterpret_cast<bf16x8*>(As0 + aw) = o0;
  }
  avA0 = __builtin_nontemporal_load(reinterpret_cast<const f32x4*>(adjrow + 64));
  avA1 = __builtin_nontemporal_load(reinterpret_cast<const f32x4*>(adjrow + 68));
  asm volatile("s_waitcnt vmcnt(2)" ::: "memory");
  asm volatile("s_waitcnt lgkmcnt(0)" ::: "memory");
  BARRIER;

  // ---- main loop: 31 ping-pong pairs (t=0..61), tail t=62, last tile t=63 ----
  for (int tp = 0; tp < 31; ++tp) {
    const int t0 = 2 * tp;
    TILE_BODY(t0,     avA0, avA1, avB0, avB1, true);
    TILE_BODY(t0 + 1, avB0, avB1, avA0, avA1, true);
  }
  TILE_BODY(62, avA0, avA1, avB0, avB1, false);
  compute(As1, Hs1);  // t=63

#undef TILE_BODY

  // ---- degree: 8 partials per row, shfl + reused LDS ----
  float d = pdeg;
  d += __shfl_xor(d, 1, 64);
  d += __shfl_xor(d, 2, 64);
  d += __shfl_xor(d, 4, 64);
  __syncthreads();  // all compute done; As region free for reuse
  if ((tid & 7) == 0) reinterpret_cast<float*>(lds)[arow] = d;
  __syncthreads();
  const float* degf = reinterpret_cast<const float*>(lds);

  // ---- epilogue: divide, NT store fp32 ----
#pragma unroll
  for (int i = 0; i < 4; ++i) {
    const int rbase = wr * 64 + i * 16 + ((lane >> 4) << 2);
    float rd[4];
#pragma unroll
    for (int r = 0; r < 4; ++r) rd[r] = 1.0f / degf[rbase + r];
#pragma unroll
    for (int j = 0; j < 4; ++j) {
      const int o = wc * 64 + j * 16 + (lane & 15);
#pragma unroll
      for (int r = 0; r < 4; ++r)
        __builtin_nontemporal_store(acc[i][j][r] * rd[r],
                                    &outb[(size_t)(m0 + rbase + r) * 512 + o]);
    }
  }
}

extern "C" void kernel_launch(void* const* d_in, const int* in_sizes, int n_in,
                              void* d_out, int out_size, void* d_ws, size_t ws_size,
                              hipStream_t stream) {
  (void)in_sizes; (void)n_in; (void)out_size; (void)ws_size;
  const float* X    = (const float*)d_in[0];  // [8,4096,512]
  const float* adj  = (const float*)d_in[1];  // [8,4096,4096]
  const float* W    = (const float*)d_in[2];  // [512,512]
  const float* bias = (const float*)d_in[3];  // [512]
  float* out = (float*)d_out;                 // [8,4096,512] fp32

  char* ws = (char*)d_ws;
  __bf16* hT = (__bf16*)ws;                                   // 32 MiB
  __bf16* Wt = (__bf16*)(ws + (size_t)32 * 1024 * 1024);      // 512 KiB

  k_wt<<<dim3(8, 8), 256, 0, stream>>>(W, Wt);
  k_proj<<<dim3(4, 256), 256, 0, stream>>>(X, Wt, bias, hT);
  k_agg<<<dim3(256), 1024, 0, stream>>>(adj, hT, out);
}